// Round 1
// baseline (382.635 us; speedup 1.0000x reference)
//
#include <hip/hip_runtime.h>

typedef __attribute__((ext_vector_type(4))) float f32x4;
typedef __attribute__((ext_vector_type(8))) __bf16 bf16x8;
typedef __attribute__((ext_vector_type(4))) __bf16 bf16x4;

#define MFMA_B16(a,b,c) __builtin_amdgcn_mfma_f32_16x16x32_bf16((a),(b),(c),0,0,0)

static constexpr int T_LEN  = 2048;
static constexpr int C_DIM  = 1024;
static constexpr int H_NUM  = 16;
static constexpr int D_HEADc = 64;

// ---------------- fp32 -> bf16 convert (vectorized) ----------------
__global__ __launch_bounds__(256) void cvt_kernel(const float* __restrict__ s,
                                                  __bf16* __restrict__ d, int n4) {
  int i = blockIdx.x * 256 + threadIdx.x;
  if (i >= n4) return;
  float4 f = reinterpret_cast<const float4*>(s)[i];
  bf16x4 o;
  o.x = (__bf16)f.x; o.y = (__bf16)f.y; o.z = (__bf16)f.z; o.w = (__bf16)f.w;
  reinterpret_cast<bf16x4*>(d)[i] = o;
}

// ---------------- GEMM1: qkv = x @ W^T + b, scatter to q/k/v [B,H,T,Dh] ----------------
// A [8192,1024] bf16 row-major, W [3072,1024] bf16 row-major (NT gemm).
// 128x128 tile, BK=64, 256 threads = 4 waves (2x2 of 64x64).
__global__ __launch_bounds__(256) void gemm_qkv(const __bf16* __restrict__ A,
                                                const __bf16* __restrict__ W,
                                                const float* __restrict__ bias,
                                                __bf16* __restrict__ qb,
                                                __bf16* __restrict__ kb,
                                                __bf16* __restrict__ vb) {
  constexpr int K = 1024;
  __shared__ __bf16 As[128 * 72];  // pad rows to 72 elems (144B) -> conflict-free b128 reads
  __shared__ __bf16 Bs[128 * 72];
  const int tid = threadIdx.x;
  const int wid = tid >> 6, lane = tid & 63, l16 = lane & 15, lg = lane >> 4;
  const int wm = wid >> 1, wn = wid & 1;
  const int m0 = blockIdx.x * 128, n0 = blockIdx.y * 128;

  f32x4 acc[4][4];
#pragma unroll
  for (int i = 0; i < 4; ++i)
#pragma unroll
    for (int j = 0; j < 4; ++j) acc[i][j] = f32x4{0.f, 0.f, 0.f, 0.f};

  for (int k0 = 0; k0 < K; k0 += 64) {
    __syncthreads();
#pragma unroll
    for (int it = 0; it < 4; ++it) {
      int c = tid + it * 256;          // 1024 chunks of 8 elems (16B)
      int row = c >> 3, col = (c & 7) * 8;
      *reinterpret_cast<uint4*>(&As[row * 72 + col]) =
          *reinterpret_cast<const uint4*>(A + (long)(m0 + row) * K + k0 + col);
      *reinterpret_cast<uint4*>(&Bs[row * 72 + col]) =
          *reinterpret_cast<const uint4*>(W + (long)(n0 + row) * K + k0 + col);
    }
    __syncthreads();
#pragma unroll
    for (int kt = 0; kt < 2; ++kt) {
      bf16x8 af[4], bfv[4];
#pragma unroll
      for (int mi = 0; mi < 4; ++mi)
        af[mi] = *reinterpret_cast<const bf16x8*>(&As[(wm * 64 + mi * 16 + l16) * 72 + kt * 32 + lg * 8]);
#pragma unroll
      for (int nt = 0; nt < 4; ++nt)
        bfv[nt] = *reinterpret_cast<const bf16x8*>(&Bs[(wn * 64 + nt * 16 + l16) * 72 + kt * 32 + lg * 8]);
#pragma unroll
      for (int mi = 0; mi < 4; ++mi)
#pragma unroll
        for (int nt = 0; nt < 4; ++nt)
          acc[mi][nt] = MFMA_B16(af[mi], bfv[nt], acc[mi][nt]);
    }
  }
  // epilogue: C[m][n]; m -> (b,t), n -> (which, h, d); D layout: col=lane&15, row=(lane>>4)*4+r
#pragma unroll
  for (int mi = 0; mi < 4; ++mi)
#pragma unroll
    for (int nt = 0; nt < 4; ++nt)
#pragma unroll
      for (int r = 0; r < 4; ++r) {
        int m = m0 + wm * 64 + mi * 16 + lg * 4 + r;
        int n = n0 + wn * 64 + nt * 16 + l16;
        float val = acc[mi][nt][r] + bias[n];
        int which = n >> 10;
        int cc = n & 1023;
        int h = cc >> 6, d = cc & 63;
        long b = m >> 11;
        long t = m & 2047;
        __bf16* dst = (which == 0) ? qb : ((which == 1) ? kb : vb);
        dst[(((b * H_NUM + h) * T_LEN) + t) * D_HEADc + d] = (__bf16)val;
      }
}

// ---------------- flash attention, causal ----------------
// grid (32, 64): x = q-tile of 64 rows, y = b*H+h. 256 thr = 4 waves; wave w owns q rows [w*16,w*16+16).
__global__ __launch_bounds__(256) void attn_kernel(const __bf16* __restrict__ q,
                                                   const __bf16* __restrict__ k,
                                                   const __bf16* __restrict__ v,
                                                   __bf16* __restrict__ y) {
  __shared__ __bf16 Ks[64 * 72];     // [kk][d] row-major, padded
  __shared__ __bf16 Vt[64 * 72];     // [d][kk] transposed, XOR-swizzled columns
  __shared__ __bf16 Ps[4][16 * 72];  // wave-private P tile [qrow][kk]
  const int tid = threadIdx.x;
  const int wid = tid >> 6, lane = tid & 63, l16 = lane & 15, lg = lane >> 4;
  const int qt = blockIdx.x;
  const int bh = blockIdx.y;
  const int q0 = qt * 64;
  const __bf16* qg = q + (long)bh * T_LEN * D_HEADc;
  const __bf16* kg = k + (long)bh * T_LEN * D_HEADc;
  const __bf16* vg = v + (long)bh * T_LEN * D_HEADc;

  bf16x8 qf[2];
#pragma unroll
  for (int kt = 0; kt < 2; ++kt)
    qf[kt] = *reinterpret_cast<const bf16x8*>(qg + (long)(q0 + wid * 16 + l16) * D_HEADc + kt * 32 + lg * 8);

  f32x4 o[4];
#pragma unroll
  for (int nt = 0; nt < 4; ++nt) o[nt] = f32x4{0.f, 0.f, 0.f, 0.f};
  float mr[4], lr[4];
#pragma unroll
  for (int r = 0; r < 4; ++r) { mr[r] = -3e38f; lr[r] = 0.f; }

  for (int t = 0; t <= qt; ++t) {
    const int k0 = t * 64;
    __syncthreads();
    // stage K row-major; stage V transposed with XOR swizzle on column (kk) index
#pragma unroll
    for (int it = 0; it < 2; ++it) {
      int c = tid + it * 256;          // 512 chunks of 8 elems
      int row = c >> 3, col = (c & 7) * 8;
      *reinterpret_cast<uint4*>(&Ks[row * 72 + col]) =
          *reinterpret_cast<const uint4*>(kg + (long)(k0 + row) * D_HEADc + col);
      uint4 vv = *reinterpret_cast<const uint4*>(vg + (long)(k0 + row) * D_HEADc + col);
      const __bf16* ve = reinterpret_cast<const __bf16*>(&vv);
#pragma unroll
      for (int i = 0; i < 8; ++i) {
        int d = col + i;
        int sc = row ^ (((d >> 3) & 7) << 3);  // swizzle kk bits 3..5 with d bits 3..5
        Vt[d * 72 + sc] = ve[i];
      }
    }
    __syncthreads();

    // S = (Q K^T) * 1/8  ; per wave: 16 rows x 64 cols
    f32x4 s[4];
#pragma unroll
    for (int nt = 0; nt < 4; ++nt) {
      s[nt] = f32x4{0.f, 0.f, 0.f, 0.f};
#pragma unroll
      for (int kt = 0; kt < 2; ++kt) {
        bf16x8 kf = *reinterpret_cast<const bf16x8*>(&Ks[(nt * 16 + l16) * 72 + kt * 32 + lg * 8]);
        s[nt] = MFMA_B16(qf[kt], kf, s[nt]);
      }
    }

    const bool diag = (k0 == q0);
    float p[4][4];
    float mt[4];
#pragma unroll
    for (int r = 0; r < 4; ++r) {
      int qrow = q0 + wid * 16 + lg * 4 + r;
      float mx = -3e38f;
#pragma unroll
      for (int nt = 0; nt < 4; ++nt) {
        float sv = s[nt][r] * 0.125f;
        if (diag && (k0 + nt * 16 + l16) > qrow) sv = -3e38f;
        p[nt][r] = sv;
        mx = fmaxf(mx, sv);
      }
      mt[r] = mx;
    }
#pragma unroll
    for (int r = 0; r < 4; ++r) {
      float mx = mt[r];
#pragma unroll
      for (int off = 1; off < 16; off <<= 1) mx = fmaxf(mx, __shfl_xor(mx, off));
      float mn = fmaxf(mr[r], mx);
      float alpha = __expf(mr[r] - mn);
      mr[r] = mn;
      float ls = 0.f;
#pragma unroll
      for (int nt = 0; nt < 4; ++nt) {
        float pv = __expf(p[nt][r] - mn);
        p[nt][r] = pv;
        ls += pv;
      }
#pragma unroll
      for (int off = 1; off < 16; off <<= 1) ls += __shfl_xor(ls, off);
      lr[r] = lr[r] * alpha + ls;
#pragma unroll
      for (int nt = 0; nt < 4; ++nt) o[nt][r] *= alpha;
    }

    // P (D-layout) -> wave-private LDS -> A-fragment layout
#pragma unroll
    for (int r = 0; r < 4; ++r)
#pragma unroll
      for (int nt = 0; nt < 4; ++nt)
        Ps[wid][(lg * 4 + r) * 72 + nt * 16 + l16] = (__bf16)p[nt][r];

    bf16x8 pf[2];
#pragma unroll
    for (int kt = 0; kt < 2; ++kt)
      pf[kt] = *reinterpret_cast<const bf16x8*>(&Ps[wid][l16 * 72 + kt * 32 + lg * 8]);

    // O += P @ V  (V read from transposed+swizzled LDS as contiguous b128)
#pragma unroll
    for (int nt = 0; nt < 4; ++nt) {
      int d = nt * 16 + l16;
#pragma unroll
      for (int kt = 0; kt < 2; ++kt) {
        int kbase = ((kt * 4 + lg) ^ ((d >> 3) & 7)) * 8;
        bf16x8 vf = *reinterpret_cast<const bf16x8*>(&Vt[d * 72 + kbase]);
        o[nt] = MFMA_B16(pf[kt], vf, o[nt]);
      }
    }
  }

  // write O/l to y [B,T,C] bf16
  long b = bh >> 4;
  int h = bh & 15;
#pragma unroll
  for (int r = 0; r < 4; ++r) {
    float inv = 1.f / lr[r];
    long row = b * T_LEN + q0 + wid * 16 + lg * 4 + r;
#pragma unroll
    for (int nt = 0; nt < 4; ++nt)
      y[row * C_DIM + h * D_HEADc + nt * 16 + l16] = (__bf16)(o[nt][r] * inv);
  }
}

// ---------------- GEMM2: out = yb @ out_w^T + out_b (fp32 out) ----------------
__global__ __launch_bounds__(256) void gemm_proj(const __bf16* __restrict__ A,
                                                 const __bf16* __restrict__ W,
                                                 const float* __restrict__ bias,
                                                 float* __restrict__ out) {
  constexpr int K = 1024;
  __shared__ __bf16 As[128 * 72];
  __shared__ __bf16 Bs[128 * 72];
  const int tid = threadIdx.x;
  const int wid = tid >> 6, lane = tid & 63, l16 = lane & 15, lg = lane >> 4;
  const int wm = wid >> 1, wn = wid & 1;
  const int m0 = blockIdx.x * 128, n0 = blockIdx.y * 128;

  f32x4 acc[4][4];
#pragma unroll
  for (int i = 0; i < 4; ++i)
#pragma unroll
    for (int j = 0; j < 4; ++j) acc[i][j] = f32x4{0.f, 0.f, 0.f, 0.f};

  for (int k0 = 0; k0 < K; k0 += 64) {
    __syncthreads();
#pragma unroll
    for (int it = 0; it < 4; ++it) {
      int c = tid + it * 256;
      int row = c >> 3, col = (c & 7) * 8;
      *reinterpret_cast<uint4*>(&As[row * 72 + col]) =
          *reinterpret_cast<const uint4*>(A + (long)(m0 + row) * K + k0 + col);
      *reinterpret_cast<uint4*>(&Bs[row * 72 + col]) =
          *reinterpret_cast<const uint4*>(W + (long)(n0 + row) * K + k0 + col);
    }
    __syncthreads();
#pragma unroll
    for (int kt = 0; kt < 2; ++kt) {
      bf16x8 af[4], bfv[4];
#pragma unroll
      for (int mi = 0; mi < 4; ++mi)
        af[mi] = *reinterpret_cast<const bf16x8*>(&As[(wm * 64 + mi * 16 + l16) * 72 + kt * 32 + lg * 8]);
#pragma unroll
      for (int nt = 0; nt < 4; ++nt)
        bfv[nt] = *reinterpret_cast<const bf16x8*>(&Bs[(wn * 64 + nt * 16 + l16) * 72 + kt * 32 + lg * 8]);
#pragma unroll
      for (int mi = 0; mi < 4; ++mi)
#pragma unroll
        for (int nt = 0; nt < 4; ++nt)
          acc[mi][nt] = MFMA_B16(af[mi], bfv[nt], acc[mi][nt]);
    }
  }
#pragma unroll
  for (int mi = 0; mi < 4; ++mi)
#pragma unroll
    for (int nt = 0; nt < 4; ++nt)
#pragma unroll
      for (int r = 0; r < 4; ++r) {
        long m = m0 + wm * 64 + mi * 16 + lg * 4 + r;
        int n = n0 + wn * 64 + nt * 16 + l16;
        out[m * C_DIM + n] = acc[mi][nt][r] + bias[n];
      }
}

extern "C" void kernel_launch(void* const* d_in, const int* in_sizes, int n_in,
                              void* d_out, int out_size, void* d_ws, size_t ws_size,
                              hipStream_t stream) {
  const float* x     = (const float*)d_in[0];
  const float* qkv_w = (const float*)d_in[1];
  const float* qkv_b = (const float*)d_in[2];
  const float* out_w = (const float*)d_in[3];
  const float* out_b = (const float*)d_in[4];
  float* out = (float*)d_out;

  const long NX  = 8192L * 1024;   // x / q / k / v / y element counts
  const long NWQ = 3072L * 1024;
  const long NWO = 1024L * 1024;
  const size_t need = (size_t)(5 * NX + NWQ + NWO) * 2;
  if (ws_size < need) return;  // diagnosable: output stays zero

  __bf16* xb   = (__bf16*)d_ws;
  __bf16* wqkv = xb + NX;
  __bf16* wout = wqkv + NWQ;
  __bf16* qb   = wout + NWO;
  __bf16* kb   = qb + NX;
  __bf16* vb   = kb + NX;
  __bf16* yb   = vb + NX;

  cvt_kernel<<<(int)(NX / 4 / 256), 256, 0, stream>>>(x, xb, (int)(NX / 4));
  cvt_kernel<<<(int)(NWQ / 4 / 256), 256, 0, stream>>>(qkv_w, wqkv, (int)(NWQ / 4));
  cvt_kernel<<<(int)(NWO / 4 / 256), 256, 0, stream>>>(out_w, wout, (int)(NWO / 4));

  gemm_qkv<<<dim3(64, 24), 256, 0, stream>>>(xb, wqkv, qkv_b, qb, kb, vb);
  attn_kernel<<<dim3(32, 64), 256, 0, stream>>>(qb, kb, vb, yb);
  gemm_proj<<<dim3(64, 8), 256, 0, stream>>>(yb, wout, out_b, out);
}

// Round 2
// 304.993 us; speedup vs baseline: 1.2546x; 1.2546x over previous
//
#include <hip/hip_runtime.h>

typedef __attribute__((ext_vector_type(4))) float f32x4;
typedef __attribute__((ext_vector_type(8))) __bf16 bf16x8;
typedef __attribute__((ext_vector_type(4))) __bf16 bf16x4;

#define MFMA_B16(a,b,c) __builtin_amdgcn_mfma_f32_16x16x32_bf16((a),(b),(c),0,0,0)

static constexpr int T_LEN  = 2048;
static constexpr int C_DIM  = 1024;
static constexpr int H_NUM  = 16;
static constexpr int D_HEADc = 64;
// fold 1/sqrt(Dh) * log2(e) into Q so softmax uses exp2
static constexpr float Q_PRESCALE = 0.125f * 1.4426950408889634f;

// ---------------- fp32 -> bf16 convert (vectorized) ----------------
__global__ __launch_bounds__(256) void cvt_kernel(const float* __restrict__ s,
                                                  __bf16* __restrict__ d, int n4) {
  int i = blockIdx.x * 256 + threadIdx.x;
  if (i >= n4) return;
  float4 f = reinterpret_cast<const float4*>(s)[i];
  bf16x4 o;
  o.x = (__bf16)f.x; o.y = (__bf16)f.y; o.z = (__bf16)f.z; o.w = (__bf16)f.w;
  reinterpret_cast<bf16x4*>(d)[i] = o;
}

// ---------------- GEMM1: qkv = x @ W^T + b ----------------
// q scattered to [B,H,T,Dh] (pre-scaled), k to [B,H,T,Dh], v TRANSPOSED to [B,H,Dh,T].
__global__ __launch_bounds__(256) void gemm_qkv(const __bf16* __restrict__ A,
                                                const __bf16* __restrict__ W,
                                                const float* __restrict__ bias,
                                                __bf16* __restrict__ qb,
                                                __bf16* __restrict__ kb,
                                                __bf16* __restrict__ vb) {
  constexpr int K = 1024;
  __shared__ __bf16 As[128 * 72];
  __shared__ __bf16 Bs[128 * 72];
  const int tid = threadIdx.x;
  const int wid = tid >> 6, lane = tid & 63, l16 = lane & 15, lg = lane >> 4;
  const int wm = wid >> 1, wn = wid & 1;
  const int m0 = blockIdx.x * 128, n0 = blockIdx.y * 128;

  f32x4 acc[4][4];
#pragma unroll
  for (int i = 0; i < 4; ++i)
#pragma unroll
    for (int j = 0; j < 4; ++j) acc[i][j] = f32x4{0.f, 0.f, 0.f, 0.f};

  for (int k0 = 0; k0 < K; k0 += 64) {
    __syncthreads();
#pragma unroll
    for (int it = 0; it < 4; ++it) {
      int c = tid + it * 256;
      int row = c >> 3, col = (c & 7) * 8;
      *reinterpret_cast<uint4*>(&As[row * 72 + col]) =
          *reinterpret_cast<const uint4*>(A + (long)(m0 + row) * K + k0 + col);
      *reinterpret_cast<uint4*>(&Bs[row * 72 + col]) =
          *reinterpret_cast<const uint4*>(W + (long)(n0 + row) * K + k0 + col);
    }
    __syncthreads();
#pragma unroll
    for (int kt = 0; kt < 2; ++kt) {
      bf16x8 af[4], bfv[4];
#pragma unroll
      for (int mi = 0; mi < 4; ++mi)
        af[mi] = *reinterpret_cast<const bf16x8*>(&As[(wm * 64 + mi * 16 + l16) * 72 + kt * 32 + lg * 8]);
#pragma unroll
      for (int nt = 0; nt < 4; ++nt)
        bfv[nt] = *reinterpret_cast<const bf16x8*>(&Bs[(wn * 64 + nt * 16 + l16) * 72 + kt * 32 + lg * 8]);
#pragma unroll
      for (int mi = 0; mi < 4; ++mi)
#pragma unroll
        for (int nt = 0; nt < 4; ++nt)
          acc[mi][nt] = MFMA_B16(af[mi], bfv[nt], acc[mi][nt]);
    }
  }
#pragma unroll
  for (int mi = 0; mi < 4; ++mi)
#pragma unroll
    for (int nt = 0; nt < 4; ++nt)
#pragma unroll
      for (int r = 0; r < 4; ++r) {
        int m = m0 + wm * 64 + mi * 16 + lg * 4 + r;
        int n = n0 + wn * 64 + nt * 16 + l16;
        float val = acc[mi][nt][r] + bias[n];
        int which = n >> 10;
        int cc = n & 1023;
        int h = cc >> 6, d = cc & 63;
        long b = m >> 11;
        long t = m & 2047;
        if (which == 0) {
          qb[(((b * H_NUM + h) * T_LEN) + t) * D_HEADc + d] = (__bf16)(val * Q_PRESCALE);
        } else if (which == 1) {
          kb[(((b * H_NUM + h) * T_LEN) + t) * D_HEADc + d] = (__bf16)val;
        } else {
          vb[(((b * H_NUM + h) * D_HEADc) + d) * T_LEN + t] = (__bf16)val;  // V^T
        }
      }
}

// ---------------- flash attention, causal ----------------
// grid (16, 64): x -> q-tile of 128 rows (reversed: heavy first), y = b*H+h.
// 256 thr = 4 waves; wave w owns 32 q rows. KV tile = 64. Swapped QK^T:
// s = mfma(K, Q) so lane's l16 = q-row; softmax is per-lane + 2 shfl_xor.
// K/V^T/P tiles in LDS, [row][64] with 16B-slot XOR swizzle (slot ^= row&7).
__global__ __launch_bounds__(256) void attn_kernel(const __bf16* __restrict__ q,
                                                   const __bf16* __restrict__ k,
                                                   const __bf16* __restrict__ vt,
                                                   __bf16* __restrict__ y) {
  __shared__ __bf16 Ks[64 * 64];
  __shared__ __bf16 Vs[64 * 64];
  __shared__ __bf16 Ps[4][32 * 64];
  const int tid = threadIdx.x;
  const int wid = tid >> 6, lane = tid & 63, l16 = lane & 15, lg = lane >> 4;
  const int qt = (int)gridDim.x - 1 - (int)blockIdx.x;
  const int bh = blockIdx.y;
  const int q0 = qt * 128;
  const int qw = q0 + wid * 32;
  const __bf16* qg = q + (long)bh * T_LEN * D_HEADc;
  const __bf16* kg = k + (long)bh * T_LEN * D_HEADc;
  const __bf16* vg = vt + (long)bh * T_LEN * D_HEADc;  // [Dh=64][T=2048]

  bf16x8 qf[2][2];
#pragma unroll
  for (int qi = 0; qi < 2; ++qi)
#pragma unroll
    for (int kt = 0; kt < 2; ++kt)
      qf[qi][kt] = *reinterpret_cast<const bf16x8*>(
          qg + (long)(qw + qi * 16 + l16) * D_HEADc + kt * 32 + lg * 8);

  f32x4 o[2][4];
#pragma unroll
  for (int qi = 0; qi < 2; ++qi)
#pragma unroll
    for (int di = 0; di < 4; ++di) o[qi][di] = f32x4{0.f, 0.f, 0.f, 0.f};
  float m[2] = {-3e38f, -3e38f}, l[2] = {0.f, 0.f};

  const int r7 = l16 & 7;  // row&7 for all fragment reads (rows are x*16 + l16)
  const int ntiles = qt * 2 + 2;
  for (int t = 0; t < ntiles; ++t) {
    const int k0 = t * 64;
    __syncthreads();
    // stage K and V^T, swizzled: LDS[row][ (slot^(row&7))*8 .. ] = G[row][slot*8 ..]
#pragma unroll
    for (int it = 0; it < 2; ++it) {
      int c = tid + it * 256;
      int row = c >> 3, sl = c & 7;
      int dsts = ((sl ^ (row & 7)) << 3);
      *reinterpret_cast<uint4*>(&Ks[row * 64 + dsts]) =
          *reinterpret_cast<const uint4*>(kg + (long)(k0 + row) * D_HEADc + (sl << 3));
      *reinterpret_cast<uint4*>(&Vs[row * 64 + dsts]) =
          *reinterpret_cast<const uint4*>(vg + (long)row * T_LEN + k0 + (sl << 3));
    }
    __syncthreads();
    if (k0 >= qw + 32) continue;  // fully masked for this wave (barrier counts still match)

    // S^T = K Q^T : s[qi][ki]; lane holds q = qw+qi*16+l16, k = k0+ki*16+lg*4+r
    f32x4 s[2][4];
#pragma unroll
    for (int qi = 0; qi < 2; ++qi)
#pragma unroll
      for (int ki = 0; ki < 4; ++ki) s[qi][ki] = f32x4{0.f, 0.f, 0.f, 0.f};
#pragma unroll
    for (int kt = 0; kt < 2; ++kt) {
      const int sw = ((((kt << 2) | lg) ^ r7) << 3);
#pragma unroll
      for (int ki = 0; ki < 4; ++ki) {
        bf16x8 kf = *reinterpret_cast<const bf16x8*>(&Ks[(ki * 16 + l16) * 64 + sw]);
        s[0][ki] = MFMA_B16(kf, qf[0][kt], s[0][ki]);
        s[1][ki] = MFMA_B16(kf, qf[1][kt], s[1][ki]);
      }
    }

    // online softmax (log2 space; Q pre-scaled by 0.125*log2e)
#pragma unroll
    for (int qi = 0; qi < 2; ++qi) {
      const int qglob = qw + qi * 16 + l16;
      const bool needMask = (k0 + 63 > qw + qi * 16);
      float pv[4][4];
      float mx = -3e38f;
#pragma unroll
      for (int ki = 0; ki < 4; ++ki)
#pragma unroll
        for (int r = 0; r < 4; ++r) {
          float sv = s[qi][ki][r];
          if (needMask && (k0 + ki * 16 + (lg << 2) + r > qglob)) sv = -3e38f;
          pv[ki][r] = sv;
          mx = fmaxf(mx, sv);
        }
      mx = fmaxf(mx, __shfl_xor(mx, 16));
      mx = fmaxf(mx, __shfl_xor(mx, 32));
      const float mn = fmaxf(m[qi], mx);
      const float al = exp2f(m[qi] - mn);
      m[qi] = mn;
      float ls = 0.f;
#pragma unroll
      for (int ki = 0; ki < 4; ++ki) {
        bf16x4 pk;
#pragma unroll
        for (int r = 0; r < 4; ++r) {
          float e = exp2f(pv[ki][r] - mn);
          ls += e;
          pk[r] = (__bf16)e;
        }
        *reinterpret_cast<bf16x4*>(
            &Ps[wid][(qi * 16 + l16) * 64 + (((ki << 4) | (lg << 2)) ^ (r7 << 3))]) = pk;
      }
      ls += __shfl_xor(ls, 16);
      ls += __shfl_xor(ls, 32);
      l[qi] = l[qi] * al + ls;
#pragma unroll
      for (int r = 0; r < 4; ++r) {
        float ar = __shfl(al, (lane & 48) | (lg << 2) | r);
#pragma unroll
        for (int di = 0; di < 4; ++di) o[qi][di][r] *= ar;
      }
    }

    // O += P @ V   (A = P rows=q; B = V^T rows=d; both k-contiguous, swizzled)
#pragma unroll
    for (int kt = 0; kt < 2; ++kt) {
      const int sw = ((((kt << 2) | lg) ^ r7) << 3);
      bf16x8 pf0 = *reinterpret_cast<const bf16x8*>(&Ps[wid][l16 * 64 + sw]);
      bf16x8 pf1 = *reinterpret_cast<const bf16x8*>(&Ps[wid][(16 + l16) * 64 + sw]);
#pragma unroll
      for (int di = 0; di < 4; ++di) {
        bf16x8 vf = *reinterpret_cast<const bf16x8*>(&Vs[(di * 16 + l16) * 64 + sw]);
        o[0][di] = MFMA_B16(pf0, vf, o[0][di]);
        o[1][di] = MFMA_B16(pf1, vf, o[1][di]);
      }
    }
  }

  // epilogue: y[B,T,C] bf16; lane holds q = lg*4+r (+qi*16), d = di*16+l16
  const long bb = bh >> 4;
  const int h = bh & 15;
#pragma unroll
  for (int qi = 0; qi < 2; ++qi)
#pragma unroll
    for (int r = 0; r < 4; ++r) {
      float lq = __shfl(l[qi], (lane & 48) | (lg << 2) | r);
      float inv = 1.f / lq;
      long row = bb * T_LEN + qw + qi * 16 + (lg << 2) + r;
#pragma unroll
      for (int di = 0; di < 4; ++di)
        y[row * C_DIM + h * D_HEADc + di * 16 + l16] = (__bf16)(o[qi][di][r] * inv);
    }
}

// ---------------- GEMM2: out = yb @ out_w^T + out_b (fp32 out) ----------------
__global__ __launch_bounds__(256) void gemm_proj(const __bf16* __restrict__ A,
                                                 const __bf16* __restrict__ W,
                                                 const float* __restrict__ bias,
                                                 float* __restrict__ out) {
  constexpr int K = 1024;
  __shared__ __bf16 As[128 * 72];
  __shared__ __bf16 Bs[128 * 72];
  const int tid = threadIdx.x;
  const int wid = tid >> 6, lane = tid & 63, l16 = lane & 15, lg = lane >> 4;
  const int wm = wid >> 1, wn = wid & 1;
  const int m0 = blockIdx.x * 128, n0 = blockIdx.y * 128;

  f32x4 acc[4][4];
#pragma unroll
  for (int i = 0; i < 4; ++i)
#pragma unroll
    for (int j = 0; j < 4; ++j) acc[i][j] = f32x4{0.f, 0.f, 0.f, 0.f};

  for (int k0 = 0; k0 < K; k0 += 64) {
    __syncthreads();
#pragma unroll
    for (int it = 0; it < 4; ++it) {
      int c = tid + it * 256;
      int row = c >> 3, col = (c & 7) * 8;
      *reinterpret_cast<uint4*>(&As[row * 72 + col]) =
          *reinterpret_cast<const uint4*>(A + (long)(m0 + row) * K + k0 + col);
      *reinterpret_cast<uint4*>(&Bs[row * 72 + col]) =
          *reinterpret_cast<const uint4*>(W + (long)(n0 + row) * K + k0 + col);
    }
    __syncthreads();
#pragma unroll
    for (int kt = 0; kt < 2; ++kt) {
      bf16x8 af[4], bfv[4];
#pragma unroll
      for (int mi = 0; mi < 4; ++mi)
        af[mi] = *reinterpret_cast<const bf16x8*>(&As[(wm * 64 + mi * 16 + l16) * 72 + kt * 32 + lg * 8]);
#pragma unroll
      for (int nt = 0; nt < 4; ++nt)
        bfv[nt] = *reinterpret_cast<const bf16x8*>(&Bs[(wn * 64 + nt * 16 + l16) * 72 + kt * 32 + lg * 8]);
#pragma unroll
      for (int mi = 0; mi < 4; ++mi)
#pragma unroll
        for (int nt = 0; nt < 4; ++nt)
          acc[mi][nt] = MFMA_B16(af[mi], bfv[nt], acc[mi][nt]);
    }
  }
#pragma unroll
  for (int mi = 0; mi < 4; ++mi)
#pragma unroll
    for (int nt = 0; nt < 4; ++nt)
#pragma unroll
      for (int r = 0; r < 4; ++r) {
        long m = m0 + wm * 64 + mi * 16 + lg * 4 + r;
        int n = n0 + wn * 64 + nt * 16 + l16;
        out[m * C_DIM + n] = acc[mi][nt][r] + bias[n];
      }
}

extern "C" void kernel_launch(void* const* d_in, const int* in_sizes, int n_in,
                              void* d_out, int out_size, void* d_ws, size_t ws_size,
                              hipStream_t stream) {
  const float* x     = (const float*)d_in[0];
  const float* qkv_w = (const float*)d_in[1];
  const float* qkv_b = (const float*)d_in[2];
  const float* out_w = (const float*)d_in[3];
  const float* out_b = (const float*)d_in[4];
  float* out = (float*)d_out;

  const long NX  = 8192L * 1024;
  const long NWQ = 3072L * 1024;
  const long NWO = 1024L * 1024;
  const size_t need = (size_t)(5 * NX + NWQ + NWO) * 2;
  if (ws_size < need) return;

  __bf16* xb   = (__bf16*)d_ws;
  __bf16* wqkv = xb + NX;
  __bf16* wout = wqkv + NWQ;
  __bf16* qb   = wout + NWO;
  __bf16* kb   = qb + NX;
  __bf16* vb   = kb + NX;   // V^T [B,H,Dh,T]
  __bf16* yb   = vb + NX;

  cvt_kernel<<<(int)(NX / 4 / 256), 256, 0, stream>>>(x, xb, (int)(NX / 4));
  cvt_kernel<<<(int)(NWQ / 4 / 256), 256, 0, stream>>>(qkv_w, wqkv, (int)(NWQ / 4));
  cvt_kernel<<<(int)(NWO / 4 / 256), 256, 0, stream>>>(out_w, wout, (int)(NWO / 4));

  gemm_qkv<<<dim3(64, 24), 256, 0, stream>>>(xb, wqkv, qkv_b, qb, kb, vb);
  attn_kernel<<<dim3(16, 64), 256, 0, stream>>>(qb, kb, vb, yb);
  gemm_proj<<<dim3(64, 8), 256, 0, stream>>>(yb, wout, out_b, out);
}

// Round 3
// 203.834 us; speedup vs baseline: 1.8772x; 1.4963x over previous
//
#include <hip/hip_runtime.h>

typedef __attribute__((ext_vector_type(4))) float f32x4;
typedef __attribute__((ext_vector_type(8))) __bf16 bf16x8;
typedef __attribute__((ext_vector_type(4))) __bf16 bf16x4;

#define MFMA_B16(a,b,c) __builtin_amdgcn_mfma_f32_16x16x32_bf16((a),(b),(c),0,0,0)

static constexpr int T_LEN  = 2048;
static constexpr int C_DIM  = 1024;
static constexpr int H_NUM  = 16;
static constexpr int D_HEADc = 64;
// fold 1/sqrt(Dh) * log2(e) into Q so softmax uses exp2
static constexpr float Q_PRESCALE = 0.125f * 1.4426950408889634f;

// async global->LDS, 16B per lane. LDS dest = wave-uniform base + lane*16.
__device__ __forceinline__ void async16(const void* g, void* l) {
  __builtin_amdgcn_global_load_lds(
      (const __attribute__((address_space(1))) unsigned int*)g,
      (__attribute__((address_space(3))) unsigned int*)l, 16, 0, 0);
}

// ---------------- fp32 -> bf16 convert (vectorized) ----------------
__global__ __launch_bounds__(256) void cvt_kernel(const float* __restrict__ s,
                                                  __bf16* __restrict__ d, int n4) {
  int i = blockIdx.x * 256 + threadIdx.x;
  if (i >= n4) return;
  float4 f = reinterpret_cast<const float4*>(s)[i];
  bf16x4 o;
  o.x = (__bf16)f.x; o.y = (__bf16)f.y; o.z = (__bf16)f.z; o.w = (__bf16)f.w;
  reinterpret_cast<bf16x4*>(d)[i] = o;
}

// ---------------- GEMM1: qkv = x @ W^T + b ----------------
// m97 structure: global_load_lds w16, [128][64] XOR-swizzled LDS, 2-barrier K-loop.
// q -> [B,H,T,Dh] pre-scaled, k -> [B,H,T,Dh], v -> TRANSPOSED [B,H,Dh,T].
__global__ __launch_bounds__(256) void gemm_qkv(const __bf16* __restrict__ A,
                                                const __bf16* __restrict__ W,
                                                const float* __restrict__ bias,
                                                __bf16* __restrict__ qb,
                                                __bf16* __restrict__ kb,
                                                __bf16* __restrict__ vb) {
  constexpr int K = 1024;
  __shared__ __bf16 As[128 * 64];
  __shared__ __bf16 Bs[128 * 64];
  const int tid = threadIdx.x;
  const int wid = tid >> 6, lane = tid & 63, l16 = lane & 15, lg = lane >> 4;
  const int r8 = lane >> 3, sl = lane & 7;
  const int r7 = l16 & 7;
  const int wm = wid >> 1, wn = wid & 1;
  const int m0 = blockIdx.x * 128, n0 = blockIdx.y * 128;

  f32x4 acc[4][4];
#pragma unroll
  for (int i = 0; i < 4; ++i)
#pragma unroll
    for (int j = 0; j < 4; ++j) acc[i][j] = f32x4{0.f, 0.f, 0.f, 0.f};

  for (int k0 = 0; k0 < K; k0 += 64) {
    __builtin_amdgcn_s_barrier();  // prev compute done before overwrite
#pragma unroll
    for (int it = 0; it < 4; ++it) {
      int chunk = it * 4 + wid;          // 16 chunks of 8 rows
      int row = chunk * 8 + r8;
      int scol = ((sl ^ (row & 7)) << 3);  // pre-swizzled source col
      async16(A + (long)(m0 + row) * K + k0 + scol, &As[chunk * 512]);
      async16(W + (long)(n0 + row) * K + k0 + scol, &Bs[chunk * 512]);
    }
    asm volatile("s_waitcnt vmcnt(0)" ::: "memory");
    __builtin_amdgcn_s_barrier();
#pragma unroll
    for (int kt = 0; kt < 2; ++kt) {
      const int sw = ((((kt << 2) | lg) ^ r7) << 3);
      bf16x8 af[4], bfv[4];
#pragma unroll
      for (int mi = 0; mi < 4; ++mi)
        af[mi] = *reinterpret_cast<const bf16x8*>(&As[(wm * 64 + mi * 16 + l16) * 64 + sw]);
#pragma unroll
      for (int nt = 0; nt < 4; ++nt)
        bfv[nt] = *reinterpret_cast<const bf16x8*>(&Bs[(wn * 64 + nt * 16 + l16) * 64 + sw]);
#pragma unroll
      for (int mi = 0; mi < 4; ++mi)
#pragma unroll
        for (int nt = 0; nt < 4; ++nt)
          acc[mi][nt] = MFMA_B16(af[mi], bfv[nt], acc[mi][nt]);
    }
  }
#pragma unroll
  for (int mi = 0; mi < 4; ++mi)
#pragma unroll
    for (int nt = 0; nt < 4; ++nt)
#pragma unroll
      for (int r = 0; r < 4; ++r) {
        int m = m0 + wm * 64 + mi * 16 + lg * 4 + r;
        int n = n0 + wn * 64 + nt * 16 + l16;
        float val = acc[mi][nt][r] + bias[n];
        int which = n >> 10;
        int cc = n & 1023;
        int h = cc >> 6, d = cc & 63;
        long b = m >> 11;
        long t = m & 2047;
        if (which == 0) {
          qb[(((b * H_NUM + h) * T_LEN) + t) * D_HEADc + d] = (__bf16)(val * Q_PRESCALE);
        } else if (which == 1) {
          kb[(((b * H_NUM + h) * T_LEN) + t) * D_HEADc + d] = (__bf16)val;
        } else {
          vb[(((b * H_NUM + h) * D_HEADc) + d) * T_LEN + t] = (__bf16)val;  // V^T
        }
      }
}

// ---------------- flash attention, causal ----------------
// 1D grid, heavy-first: qt = 15 - bid/64, bh = bid%64. 4 waves, 32 q-rows/wave.
// KV tile 64, double-buffered via global_load_lds + counted vmcnt.
__global__ __launch_bounds__(256) void attn_kernel(const __bf16* __restrict__ q,
                                                   const __bf16* __restrict__ k,
                                                   const __bf16* __restrict__ vt,
                                                   __bf16* __restrict__ y) {
  __shared__ __bf16 Ks[2][64 * 64];
  __shared__ __bf16 Vs[2][64 * 64];
  __shared__ __bf16 Ps[4][32 * 64];
  const int tid = threadIdx.x;
  const int wid = tid >> 6, lane = tid & 63, l16 = lane & 15, lg = lane >> 4;
  const int r8 = lane >> 3, sl = lane & 7;
  const int r7 = l16 & 7;
  const int bid = blockIdx.x;
  const int qt = 15 - (bid >> 6);
  const int bh = bid & 63;
  const int q0 = qt * 128;
  const int qw = q0 + wid * 32;
  const __bf16* qg = q + (long)bh * T_LEN * D_HEADc;
  const __bf16* kg = k + (long)bh * T_LEN * D_HEADc;
  const __bf16* vg = vt + (long)bh * T_LEN * D_HEADc;  // [Dh=64][T=2048]

  bf16x8 qf[2][2];
#pragma unroll
  for (int qi = 0; qi < 2; ++qi)
#pragma unroll
    for (int kt = 0; kt < 2; ++kt)
      qf[qi][kt] = *reinterpret_cast<const bf16x8*>(
          qg + (long)(qw + qi * 16 + l16) * D_HEADc + kt * 32 + lg * 8);

  f32x4 o[2][4];
#pragma unroll
  for (int qi = 0; qi < 2; ++qi)
#pragma unroll
    for (int di = 0; di < 4; ++di) o[qi][di] = f32x4{0.f, 0.f, 0.f, 0.f};
  float m[2] = {-3e38f, -3e38f}, l[2] = {0.f, 0.f};

  // stage K and V^T tiles, linear LDS dest + pre-swizzled global source column
  auto stage = [&](int buf, int t) {
    const int k0s = t * 64;
#pragma unroll
    for (int it = 0; it < 2; ++it) {
      int chunk = it * 4 + wid;
      int row = chunk * 8 + r8;
      int scol = ((sl ^ (row & 7)) << 3);
      async16(kg + (long)(k0s + row) * D_HEADc + scol, &Ks[buf][chunk * 512]);
      async16(vg + (long)row * T_LEN + k0s + scol, &Vs[buf][chunk * 512]);
    }
  };

  const int ntiles = qt * 2 + 2;
  stage(0, 0);
  int cur = 0;
  for (int t = 0; t < ntiles; ++t) {
    if (t + 1 < ntiles) {
      stage(cur ^ 1, t + 1);                           // issue next-tile loads early
      asm volatile("s_waitcnt vmcnt(4)" ::: "memory"); // tile-t loads done, next in flight
    } else {
      asm volatile("s_waitcnt vmcnt(0)" ::: "memory");
    }
    __builtin_amdgcn_s_barrier();                      // all waves' tile-t data in LDS
    const int k0 = t * 64;
    if (k0 < qw + 32) {
      // S^T = K Q^T : lane = q-row l16 (+qi*16); k = ki*16 + lg*4 + r
      f32x4 s[2][4];
#pragma unroll
      for (int qi = 0; qi < 2; ++qi)
#pragma unroll
        for (int ki = 0; ki < 4; ++ki) s[qi][ki] = f32x4{0.f, 0.f, 0.f, 0.f};
      __builtin_amdgcn_s_setprio(1);
#pragma unroll
      for (int kt = 0; kt < 2; ++kt) {
        const int sw = ((((kt << 2) | lg) ^ r7) << 3);
#pragma unroll
        for (int ki = 0; ki < 4; ++ki) {
          bf16x8 kf = *reinterpret_cast<const bf16x8*>(&Ks[cur][(ki * 16 + l16) * 64 + sw]);
          s[0][ki] = MFMA_B16(kf, qf[0][kt], s[0][ki]);
          s[1][ki] = MFMA_B16(kf, qf[1][kt], s[1][ki]);
        }
      }
      __builtin_amdgcn_s_setprio(0);

      // online softmax in log2 space with defer-max (THR=8)
#pragma unroll
      for (int qi = 0; qi < 2; ++qi) {
        const int qglob = qw + qi * 16 + l16;
        const bool needMask = (k0 + 63 > qw + qi * 16);  // wave-uniform
        float pv[4][4];
        float mx = -3e38f;
        if (needMask) {
#pragma unroll
          for (int ki = 0; ki < 4; ++ki)
#pragma unroll
            for (int r = 0; r < 4; ++r) {
              float sv = s[qi][ki][r];
              if (k0 + ki * 16 + (lg << 2) + r > qglob) sv = -3e38f;
              pv[ki][r] = sv;
              mx = fmaxf(mx, sv);
            }
        } else {
#pragma unroll
          for (int ki = 0; ki < 4; ++ki)
#pragma unroll
            for (int r = 0; r < 4; ++r) {
              float sv = s[qi][ki][r];
              pv[ki][r] = sv;
              mx = fmaxf(mx, sv);
            }
        }
        mx = fmaxf(mx, __shfl_xor(mx, 16));
        mx = fmaxf(mx, __shfl_xor(mx, 32));
        if (!__all(mx <= m[qi] + 8.f)) {  // defer-max: rescale only on real growth
          const float mn = fmaxf(m[qi], mx);
          const float al = exp2f(m[qi] - mn);
          m[qi] = mn;
          l[qi] *= al;
#pragma unroll
          for (int r = 0; r < 4; ++r) {
            float ar = __shfl(al, (lane & 48) | (lg << 2) | r);
#pragma unroll
            for (int di = 0; di < 4; ++di) o[qi][di][r] *= ar;
          }
        }
        float ls = 0.f;
#pragma unroll
        for (int ki = 0; ki < 4; ++ki) {
          bf16x4 pk;
#pragma unroll
          for (int r = 0; r < 4; ++r) {
            float e = exp2f(pv[ki][r] - m[qi]);
            ls += e;
            pk[r] = (__bf16)e;
          }
          *reinterpret_cast<bf16x4*>(
              &Ps[wid][(qi * 16 + l16) * 64 + (((ki << 4) | (lg << 2)) ^ (r7 << 3))]) = pk;
        }
        ls += __shfl_xor(ls, 16);
        ls += __shfl_xor(ls, 32);
        l[qi] += ls;
      }

      // O += P @ V
      __builtin_amdgcn_s_setprio(1);
#pragma unroll
      for (int kt = 0; kt < 2; ++kt) {
        const int sw = ((((kt << 2) | lg) ^ r7) << 3);
        bf16x8 pf0 = *reinterpret_cast<const bf16x8*>(&Ps[wid][l16 * 64 + sw]);
        bf16x8 pf1 = *reinterpret_cast<const bf16x8*>(&Ps[wid][(16 + l16) * 64 + sw]);
#pragma unroll
        for (int di = 0; di < 4; ++di) {
          bf16x8 vf = *reinterpret_cast<const bf16x8*>(&Vs[cur][(di * 16 + l16) * 64 + sw]);
          o[0][di] = MFMA_B16(pf0, vf, o[0][di]);
          o[1][di] = MFMA_B16(pf1, vf, o[1][di]);
        }
      }
      __builtin_amdgcn_s_setprio(0);
    }
    __builtin_amdgcn_s_barrier();  // all waves done reading buf[cur]
    cur ^= 1;
  }

  // epilogue: y[B,T,C] bf16; lane holds q = lg*4+r (+qi*16), d = di*16+l16
  const long bb = bh >> 4;
  const int h = bh & 15;
#pragma unroll
  for (int qi = 0; qi < 2; ++qi)
#pragma unroll
    for (int r = 0; r < 4; ++r) {
      float lq = __shfl(l[qi], (lane & 48) | (lg << 2) | r);
      float inv = 1.f / lq;
      long row = bb * T_LEN + qw + qi * 16 + (lg << 2) + r;
#pragma unroll
      for (int di = 0; di < 4; ++di)
        y[row * C_DIM + h * D_HEADc + di * 16 + l16] = (__bf16)(o[qi][di][r] * inv);
    }
}

// ---------------- GEMM2: out = yb @ out_w^T + out_b (fp32 out) ----------------
__global__ __launch_bounds__(256) void gemm_proj(const __bf16* __restrict__ A,
                                                 const __bf16* __restrict__ W,
                                                 const float* __restrict__ bias,
                                                 float* __restrict__ out) {
  constexpr int K = 1024;
  __shared__ __bf16 As[128 * 64];
  __shared__ __bf16 Bs[128 * 64];
  const int tid = threadIdx.x;
  const int wid = tid >> 6, lane = tid & 63, l16 = lane & 15, lg = lane >> 4;
  const int r8 = lane >> 3, sl = lane & 7;
  const int r7 = l16 & 7;
  const int wm = wid >> 1, wn = wid & 1;
  const int m0 = blockIdx.x * 128, n0 = blockIdx.y * 128;

  f32x4 acc[4][4];
#pragma unroll
  for (int i = 0; i < 4; ++i)
#pragma unroll
    for (int j = 0; j < 4; ++j) acc[i][j] = f32x4{0.f, 0.f, 0.f, 0.f};

  for (int k0 = 0; k0 < K; k0 += 64) {
    __builtin_amdgcn_s_barrier();
#pragma unroll
    for (int it = 0; it < 4; ++it) {
      int chunk = it * 4 + wid;
      int row = chunk * 8 + r8;
      int scol = ((sl ^ (row & 7)) << 3);
      async16(A + (long)(m0 + row) * K + k0 + scol, &As[chunk * 512]);
      async16(W + (long)(n0 + row) * K + k0 + scol, &Bs[chunk * 512]);
    }
    asm volatile("s_waitcnt vmcnt(0)" ::: "memory");
    __builtin_amdgcn_s_barrier();
#pragma unroll
    for (int kt = 0; kt < 2; ++kt) {
      const int sw = ((((kt << 2) | lg) ^ r7) << 3);
      bf16x8 af[4], bfv[4];
#pragma unroll
      for (int mi = 0; mi < 4; ++mi)
        af[mi] = *reinterpret_cast<const bf16x8*>(&As[(wm * 64 + mi * 16 + l16) * 64 + sw]);
#pragma unroll
      for (int nt = 0; nt < 4; ++nt)
        bfv[nt] = *reinterpret_cast<const bf16x8*>(&Bs[(wn * 64 + nt * 16 + l16) * 64 + sw]);
#pragma unroll
      for (int mi = 0; mi < 4; ++mi)
#pragma unroll
        for (int nt = 0; nt < 4; ++nt)
          acc[mi][nt] = MFMA_B16(af[mi], bfv[nt], acc[mi][nt]);
    }
  }
#pragma unroll
  for (int mi = 0; mi < 4; ++mi)
#pragma unroll
    for (int nt = 0; nt < 4; ++nt)
#pragma unroll
      for (int r = 0; r < 4; ++r) {
        long m = m0 + wm * 64 + mi * 16 + lg * 4 + r;
        int n = n0 + wn * 64 + nt * 16 + l16;
        out[m * C_DIM + n] = acc[mi][nt][r] + bias[n];
      }
}

extern "C" void kernel_launch(void* const* d_in, const int* in_sizes, int n_in,
                              void* d_out, int out_size, void* d_ws, size_t ws_size,
                              hipStream_t stream) {
  const float* x     = (const float*)d_in[0];
  const float* qkv_w = (const float*)d_in[1];
  const float* qkv_b = (const float*)d_in[2];
  const float* out_w = (const float*)d_in[3];
  const float* out_b = (const float*)d_in[4];
  float* out = (float*)d_out;

  const long NX  = 8192L * 1024;
  const long NWQ = 3072L * 1024;
  const long NWO = 1024L * 1024;
  const size_t need = (size_t)(5 * NX + NWQ + NWO) * 2;
  if (ws_size < need) return;

  __bf16* xb   = (__bf16*)d_ws;
  __bf16* wqkv = xb + NX;
  __bf16* wout = wqkv + NWQ;
  __bf16* qb   = wout + NWO;
  __bf16* kb   = qb + NX;
  __bf16* vb   = kb + NX;   // V^T [B,H,Dh,T]
  __bf16* yb   = vb + NX;

  cvt_kernel<<<(int)(NX / 4 / 256), 256, 0, stream>>>(x, xb, (int)(NX / 4));
  cvt_kernel<<<(int)(NWQ / 4 / 256), 256, 0, stream>>>(qkv_w, wqkv, (int)(NWQ / 4));
  cvt_kernel<<<(int)(NWO / 4 / 256), 256, 0, stream>>>(out_w, wout, (int)(NWO / 4));

  gemm_qkv<<<dim3(64, 24), 256, 0, stream>>>(xb, wqkv, qkv_b, qb, kb, vb);
  attn_kernel<<<dim3(1024), 256, 0, stream>>>(qb, kb, vb, yb);
  gemm_proj<<<dim3(64, 8), 256, 0, stream>>>(yb, wout, out_b, out);
}

// Round 4
// 196.424 us; speedup vs baseline: 1.9480x; 1.0377x over previous
//
#include <hip/hip_runtime.h>

typedef __attribute__((ext_vector_type(4))) float f32x4;
typedef __attribute__((ext_vector_type(16))) float f32x16;
typedef __attribute__((ext_vector_type(8))) __bf16 bf16x8;
typedef __attribute__((ext_vector_type(4))) __bf16 bf16x4;
typedef __attribute__((ext_vector_type(2))) unsigned u32x2;

#define MFMA_B16(a,b,c) __builtin_amdgcn_mfma_f32_16x16x32_bf16((a),(b),(c),0,0,0)
#define MFMA32(a,b,c)  __builtin_amdgcn_mfma_f32_32x32x16_bf16((a),(b),(c),0,0,0)

static constexpr int T_LEN  = 2048;
static constexpr int C_DIM  = 1024;
static constexpr int H_NUM  = 16;
static constexpr int D_HEADc = 64;
// fold 1/sqrt(Dh) * log2(e) into Q so softmax uses exp2
static constexpr float Q_PRESCALE = 0.125f * 1.4426950408889634f;

// async global->LDS, 16B per lane. LDS dest = wave-uniform base + lane*16.
__device__ __forceinline__ void async16(const void* g, void* l) {
  __builtin_amdgcn_global_load_lds(
      (const __attribute__((address_space(1))) unsigned int*)g,
      (__attribute__((address_space(3))) unsigned int*)l, 16, 0, 0);
}

__device__ __forceinline__ unsigned cvtpk(float lo, float hi) {
  unsigned r;
  asm("v_cvt_pk_bf16_f32 %0, %1, %2" : "=v"(r) : "v"(lo), "v"(hi));
  return r;
}

// ---------------- fp32 -> bf16 convert (vectorized) ----------------
__global__ __launch_bounds__(256) void cvt_kernel(const float* __restrict__ s,
                                                  __bf16* __restrict__ d, int n4) {
  int i = blockIdx.x * 256 + threadIdx.x;
  if (i >= n4) return;
  float4 f = reinterpret_cast<const float4*>(s)[i];
  bf16x4 o;
  o.x = (__bf16)f.x; o.y = (__bf16)f.y; o.z = (__bf16)f.z; o.w = (__bf16)f.w;
  reinterpret_cast<bf16x4*>(d)[i] = o;
}

// ---------------- GEMM1: qkv = x @ W^T + b ----------------
__global__ __launch_bounds__(256) void gemm_qkv(const __bf16* __restrict__ A,
                                                const __bf16* __restrict__ W,
                                                const float* __restrict__ bias,
                                                __bf16* __restrict__ qb,
                                                __bf16* __restrict__ kb,
                                                __bf16* __restrict__ vb) {
  constexpr int K = 1024;
  __shared__ __bf16 As[128 * 64];
  __shared__ __bf16 Bs[128 * 64];
  const int tid = threadIdx.x;
  const int wid = tid >> 6, lane = tid & 63, l16 = lane & 15, lg = lane >> 4;
  const int r8 = lane >> 3, sl = lane & 7;
  const int r7 = l16 & 7;
  const int wm = wid >> 1, wn = wid & 1;
  const int m0 = blockIdx.x * 128, n0 = blockIdx.y * 128;

  f32x4 acc[4][4];
#pragma unroll
  for (int i = 0; i < 4; ++i)
#pragma unroll
    for (int j = 0; j < 4; ++j) acc[i][j] = f32x4{0.f, 0.f, 0.f, 0.f};

  for (int k0 = 0; k0 < K; k0 += 64) {
    __builtin_amdgcn_s_barrier();
#pragma unroll
    for (int it = 0; it < 4; ++it) {
      int chunk = it * 4 + wid;
      int row = chunk * 8 + r8;
      int scol = ((sl ^ (row & 7)) << 3);
      async16(A + (long)(m0 + row) * K + k0 + scol, &As[chunk * 512]);
      async16(W + (long)(n0 + row) * K + k0 + scol, &Bs[chunk * 512]);
    }
    asm volatile("s_waitcnt vmcnt(0)" ::: "memory");
    __builtin_amdgcn_s_barrier();
#pragma unroll
    for (int kt = 0; kt < 2; ++kt) {
      const int sw = ((((kt << 2) | lg) ^ r7) << 3);
      bf16x8 af[4], bfv[4];
#pragma unroll
      for (int mi = 0; mi < 4; ++mi)
        af[mi] = *reinterpret_cast<const bf16x8*>(&As[(wm * 64 + mi * 16 + l16) * 64 + sw]);
#pragma unroll
      for (int nt = 0; nt < 4; ++nt)
        bfv[nt] = *reinterpret_cast<const bf16x8*>(&Bs[(wn * 64 + nt * 16 + l16) * 64 + sw]);
#pragma unroll
      for (int mi = 0; mi < 4; ++mi)
#pragma unroll
        for (int nt = 0; nt < 4; ++nt)
          acc[mi][nt] = MFMA_B16(af[mi], bfv[nt], acc[mi][nt]);
    }
  }
#pragma unroll
  for (int mi = 0; mi < 4; ++mi)
#pragma unroll
    for (int nt = 0; nt < 4; ++nt)
#pragma unroll
      for (int r = 0; r < 4; ++r) {
        int m = m0 + wm * 64 + mi * 16 + lg * 4 + r;
        int n = n0 + wn * 64 + nt * 16 + l16;
        float val = acc[mi][nt][r] + bias[n];
        int which = n >> 10;
        int cc = n & 1023;
        int h = cc >> 6, d = cc & 63;
        long b = m >> 11;
        long t = m & 2047;
        if (which == 0) {
          qb[(((b * H_NUM + h) * T_LEN) + t) * D_HEADc + d] = (__bf16)(val * Q_PRESCALE);
        } else if (which == 1) {
          kb[(((b * H_NUM + h) * T_LEN) + t) * D_HEADc + d] = (__bf16)val;
        } else {
          vb[(((b * H_NUM + h) * D_HEADc) + d) * T_LEN + t] = (__bf16)val;  // V^T
        }
      }
}

// ---------------- flash attention, causal, 32x32 MFMA + in-register P ----------------
// 1D grid heavy-first. 4 waves x 32 q-rows. KV tile 64, dbuf global_load_lds + vmcnt(4).
// Swapped QK^T: s = mfma32(K, Q) -> lane&31 = q-row; k = (r&3)+8*(r>>2)+4*hi.
// P->bf16 via v_cvt_pk + permlane32_swap (no P LDS). PV: o = mfma32(V^T, P^T).
__global__ __launch_bounds__(256) void attn_kernel(const __bf16* __restrict__ q,
                                                   const __bf16* __restrict__ k,
                                                   const __bf16* __restrict__ vt,
                                                   __bf16* __restrict__ y) {
  __shared__ __bf16 Ks[2][64 * 64];
  __shared__ __bf16 Vs[2][64 * 64];
  const int tid = threadIdx.x;
  const int wid = tid >> 6, lane = tid & 63;
  const int l31 = lane & 31, hi = lane >> 5;
  const int r8 = lane >> 3, sl = lane & 7;
  const int r7 = l31 & 7;
  const int bid = blockIdx.x;
  const int qt = 15 - (bid >> 6);
  const int bh = bid & 63;
  const int q0 = qt * 128;
  const int qw = q0 + wid * 32;
  const int qglob = qw + l31;
  const __bf16* qg = q + (long)bh * T_LEN * D_HEADc;
  const __bf16* kg = k + (long)bh * T_LEN * D_HEADc;
  const __bf16* vg = vt + (long)bh * T_LEN * D_HEADc;  // [Dh=64][T=2048]

  // Q as B-operand frags: lane (q=l31, hi) holds d = dt*16 + hi*8 + j
  bf16x8 qf[4];
#pragma unroll
  for (int dt = 0; dt < 4; ++dt)
    qf[dt] = *reinterpret_cast<const bf16x8*>(
        qg + (long)qglob * D_HEADc + dt * 16 + hi * 8);

  f32x16 o[2];
#pragma unroll
  for (int di = 0; di < 2; ++di)
#pragma unroll
    for (int r = 0; r < 16; ++r) o[di][r] = 0.f;
  float m = -3e38f, l = 0.f;

  auto stage = [&](int buf, int t) {
    const int k0s = t * 64;
#pragma unroll
    for (int it = 0; it < 2; ++it) {
      int chunk = it * 4 + wid;
      int row = chunk * 8 + r8;
      int scol = ((sl ^ (row & 7)) << 3);
      async16(kg + (long)(k0s + row) * D_HEADc + scol, &Ks[buf][chunk * 512]);
      async16(vg + (long)row * T_LEN + k0s + scol, &Vs[buf][chunk * 512]);
    }
  };

  const int ntiles = qt * 2 + 2;
  stage(0, 0);
  int cur = 0;
  for (int t = 0; t < ntiles; ++t) {
    if (t + 1 < ntiles) {
      stage(cur ^ 1, t + 1);
      asm volatile("s_waitcnt vmcnt(4)" ::: "memory");
    } else {
      asm volatile("s_waitcnt vmcnt(0)" ::: "memory");
    }
    __builtin_amdgcn_s_barrier();
    const int k0 = t * 64;
    if (k0 < qw + 32) {
      // ---- QK^T: s[ki] = K[ki-block] . Q, 8 mfma32 ----
      f32x16 s[2];
#pragma unroll
      for (int ki = 0; ki < 2; ++ki)
#pragma unroll
        for (int r = 0; r < 16; ++r) s[ki][r] = 0.f;
      __builtin_amdgcn_s_setprio(1);
#pragma unroll
      for (int dt = 0; dt < 4; ++dt) {
        const int swz = (((dt << 1) | hi) ^ r7) << 3;
        bf16x8 kf0 = *reinterpret_cast<const bf16x8*>(&Ks[cur][l31 * 64 + swz]);
        bf16x8 kf1 = *reinterpret_cast<const bf16x8*>(&Ks[cur][(32 + l31) * 64 + swz]);
        s[0] = MFMA32(kf0, qf[dt], s[0]);
        s[1] = MFMA32(kf1, qf[dt], s[1]);
      }
      __builtin_amdgcn_s_setprio(0);

      // ---- mask (diag tiles only) ----
      if (k0 + 63 > qw) {
#pragma unroll
        for (int r = 0; r < 16; ++r) {
          const int kb = (r & 3) + 8 * (r >> 2) + 4 * hi;
          if (k0 + kb > qglob) s[0][r] = -3e38f;
          if (k0 + 32 + kb > qglob) s[1][r] = -3e38f;
        }
      }
      // ---- online softmax (lane = q-row; one shfl across hi-halves) ----
      float mx = -3e38f;
#pragma unroll
      for (int r = 0; r < 16; ++r) mx = fmaxf(mx, fmaxf(s[0][r], s[1][r]));
      mx = fmaxf(mx, __shfl_xor(mx, 32));
      if (!__all(mx <= m + 8.f)) {  // defer-max
        const float mn = fmaxf(m, mx);
        const float al = exp2f(m - mn);
        m = mn;
        l *= al;
#pragma unroll
        for (int di = 0; di < 2; ++di)
#pragma unroll
          for (int r = 0; r < 16; ++r) o[di][r] *= al;
      }
      float ls = 0.f;
      unsigned pb[4][4];  // B-frag dwords for 4 k-depth-16 chunks
#pragma unroll
      for (int ki = 0; ki < 2; ++ki) {
#pragma unroll
        for (int r = 0; r < 16; ++r) {
          float e = exp2f(s[ki][r] - m);
          ls += e;
          s[ki][r] = e;
        }
        unsigned d0 = cvtpk(s[ki][0], s[ki][1]),   d1 = cvtpk(s[ki][2], s[ki][3]);
        unsigned d2 = cvtpk(s[ki][4], s[ki][5]),   d3 = cvtpk(s[ki][6], s[ki][7]);
        unsigned d4 = cvtpk(s[ki][8], s[ki][9]),   d5 = cvtpk(s[ki][10], s[ki][11]);
        unsigned d6 = cvtpk(s[ki][12], s[ki][13]), d7 = cvtpk(s[ki][14], s[ki][15]);
        u32x2 a = __builtin_amdgcn_permlane32_swap(d0, d2, false, false);
        u32x2 b = __builtin_amdgcn_permlane32_swap(d1, d3, false, false);
        pb[ki * 2][0] = a[0]; pb[ki * 2][1] = b[0];
        pb[ki * 2][2] = a[1]; pb[ki * 2][3] = b[1];
        u32x2 c = __builtin_amdgcn_permlane32_swap(d4, d6, false, false);
        u32x2 d = __builtin_amdgcn_permlane32_swap(d5, d7, false, false);
        pb[ki * 2 + 1][0] = c[0]; pb[ki * 2 + 1][1] = d[0];
        pb[ki * 2 + 1][2] = c[1]; pb[ki * 2 + 1][3] = d[1];
      }
      ls += __shfl_xor(ls, 32);
      l += ls;

      // ---- PV: o[di] += V^T[di-block] . P^T, 8 mfma32 ----
      __builtin_amdgcn_s_setprio(1);
#pragma unroll
      for (int kt = 0; kt < 4; ++kt) {
        union { unsigned u[4]; bf16x8 v; } pu;
        pu.u[0] = pb[kt][0]; pu.u[1] = pb[kt][1];
        pu.u[2] = pb[kt][2]; pu.u[3] = pb[kt][3];
        const int swz = (((kt << 1) | hi) ^ r7) << 3;
        bf16x8 vf0 = *reinterpret_cast<const bf16x8*>(&Vs[cur][l31 * 64 + swz]);
        bf16x8 vf1 = *reinterpret_cast<const bf16x8*>(&Vs[cur][(32 + l31) * 64 + swz]);
        o[0] = MFMA32(vf0, pu.v, o[0]);
        o[1] = MFMA32(vf1, pu.v, o[1]);
      }
      __builtin_amdgcn_s_setprio(0);
    }
    __builtin_amdgcn_s_barrier();
    cur ^= 1;
  }

  // epilogue: lane = q-row qglob; d = di*32 + 8*rr + 4*hi + c
  const long bb = bh >> 4;
  const int h = bh & 15;
  const float inv = 1.f / l;
  const long row = bb * T_LEN + qglob;
#pragma unroll
  for (int di = 0; di < 2; ++di)
#pragma unroll
    for (int rr = 0; rr < 4; ++rr) {
      bf16x4 pk;
#pragma unroll
      for (int c = 0; c < 4; ++c) pk[c] = (__bf16)(o[di][rr * 4 + c] * inv);
      *reinterpret_cast<bf16x4*>(
          &y[row * C_DIM + h * D_HEADc + di * 32 + rr * 8 + hi * 4]) = pk;
    }
}

// ---------------- GEMM2: out = yb @ out_w^T + out_b (fp32 out) ----------------
__global__ __launch_bounds__(256) void gemm_proj(const __bf16* __restrict__ A,
                                                 const __bf16* __restrict__ W,
                                                 const float* __restrict__ bias,
                                                 float* __restrict__ out) {
  constexpr int K = 1024;
  __shared__ __bf16 As[128 * 64];
  __shared__ __bf16 Bs[128 * 64];
  const int tid = threadIdx.x;
  const int wid = tid >> 6, lane = tid & 63, l16 = lane & 15, lg = lane >> 4;
  const int r8 = lane >> 3, sl = lane & 7;
  const int r7 = l16 & 7;
  const int wm = wid >> 1, wn = wid & 1;
  const int m0 = blockIdx.x * 128, n0 = blockIdx.y * 128;

  f32x4 acc[4][4];
#pragma unroll
  for (int i = 0; i < 4; ++i)
#pragma unroll
    for (int j = 0; j < 4; ++j) acc[i][j] = f32x4{0.f, 0.f, 0.f, 0.f};

  for (int k0 = 0; k0 < K; k0 += 64) {
    __builtin_amdgcn_s_barrier();
#pragma unroll
    for (int it = 0; it < 4; ++it) {
      int chunk = it * 4 + wid;
      int row = chunk * 8 + r8;
      int scol = ((sl ^ (row & 7)) << 3);
      async16(A + (long)(m0 + row) * K + k0 + scol, &As[chunk * 512]);
      async16(W + (long)(n0 + row) * K + k0 + scol, &Bs[chunk * 512]);
    }
    asm volatile("s_waitcnt vmcnt(0)" ::: "memory");
    __builtin_amdgcn_s_barrier();
#pragma unroll
    for (int kt = 0; kt < 2; ++kt) {
      const int sw = ((((kt << 2) | lg) ^ r7) << 3);
      bf16x8 af[4], bfv[4];
#pragma unroll
      for (int mi = 0; mi < 4; ++mi)
        af[mi] = *reinterpret_cast<const bf16x8*>(&As[(wm * 64 + mi * 16 + l16) * 64 + sw]);
#pragma unroll
      for (int nt = 0; nt < 4; ++nt)
        bfv[nt] = *reinterpret_cast<const bf16x8*>(&Bs[(wn * 64 + nt * 16 + l16) * 64 + sw]);
#pragma unroll
      for (int mi = 0; mi < 4; ++mi)
#pragma unroll
        for (int nt = 0; nt < 4; ++nt)
          acc[mi][nt] = MFMA_B16(af[mi], bfv[nt], acc[mi][nt]);
    }
  }
#pragma unroll
  for (int mi = 0; mi < 4; ++mi)
#pragma unroll
    for (int nt = 0; nt < 4; ++nt)
#pragma unroll
      for (int r = 0; r < 4; ++r) {
        long m = m0 + wm * 64 + mi * 16 + lg * 4 + r;
        int n = n0 + wn * 64 + nt * 16 + l16;
        out[m * C_DIM + n] = acc[mi][nt][r] + bias[n];
      }
}

extern "C" void kernel_launch(void* const* d_in, const int* in_sizes, int n_in,
                              void* d_out, int out_size, void* d_ws, size_t ws_size,
                              hipStream_t stream) {
  const float* x     = (const float*)d_in[0];
  const float* qkv_w = (const float*)d_in[1];
  const float* qkv_b = (const float*)d_in[2];
  const float* out_w = (const float*)d_in[3];
  const float* out_b = (const float*)d_in[4];
  float* out = (float*)d_out;

  const long NX  = 8192L * 1024;
  const long NWQ = 3072L * 1024;
  const long NWO = 1024L * 1024;
  const size_t need = (size_t)(5 * NX + NWQ + NWO) * 2;
  if (ws_size < need) return;

  __bf16* xb   = (__bf16*)d_ws;
  __bf16* wqkv = xb + NX;
  __bf16* wout = wqkv + NWQ;
  __bf16* qb   = wout + NWO;
  __bf16* kb   = qb + NX;
  __bf16* vb   = kb + NX;   // V^T [B,H,Dh,T]
  __bf16* yb   = vb + NX;

  cvt_kernel<<<(int)(NX / 4 / 256), 256, 0, stream>>>(x, xb, (int)(NX / 4));
  cvt_kernel<<<(int)(NWQ / 4 / 256), 256, 0, stream>>>(qkv_w, wqkv, (int)(NWQ / 4));
  cvt_kernel<<<(int)(NWO / 4 / 256), 256, 0, stream>>>(out_w, wout, (int)(NWO / 4));

  gemm_qkv<<<dim3(64, 24), 256, 0, stream>>>(xb, wqkv, qkv_b, qb, kb, vb);
  attn_kernel<<<dim3(1024), 256, 0, stream>>>(qb, kb, vb, yb);
  gemm_proj<<<dim3(64, 8), 256, 0, stream>>>(yb, wout, out_b, out);
}